// Round 12
// baseline (329.677 us; speedup 1.0000x reference)
//
#include <hip/hip_runtime.h>

#define SEQ 1024
#define NT 512   // 8 waves; wave w owns units [16w,16w+16) for r,z,n

typedef int int4v __attribute__((ext_vector_type(4)));  // i8 MFMA frags/accum

// i8 h buffer (bytes): hi8 at [0..127], dump at [256..319].
// A-reads (b128): 4 distinct addrs x 16-lane broadcast, banks 0-15 (Ai0)
// and 16-31 (Ai1): conflict-free.
#define QBUF 384

#define NLOG2E  (-1.4426950408889634f)   // -log2(e): sigmoid via exp2
#define N2LOG2E (-2.8853900817779268f)   // -2*log2(e): tanh via exp2

__global__ __launch_bounds__(NT, 2)
void gru_kernel(const float* __restrict__ x,     // [B, S, 1]
                const float* __restrict__ w_ih,  // [3H, 1]
                const float* __restrict__ w_hh,  // [3H, H]
                const float* __restrict__ b_ih,  // [3H]
                const float* __restrict__ b_hh,  // [3H]
                const float* __restrict__ w_fc,  // [1, H]
                const float* __restrict__ b_fc,  // [1]
                float* __restrict__ out)         // [B, 1]
{
  __shared__ __align__(8) float xs[SEQ + 2];
  __shared__ __align__(16) char hq[2][QBUF];
  __shared__ float red[8];

  const int t = threadIdx.x;
  const int b = blockIdx.x;
  const int w = t >> 6;          // wave 0..7
  const int L = t & 63;          // lane
  const int n = L & 15;          // MFMA col (unit) == A-row
  const int quad = L >> 4;       // k-slice / C-row group
  const int u = 16 * w + n;      // hidden unit

  // stage x[b,:] (coalesced); pad 2 zeros for the register prefetch
  const float* xrow = x + (size_t)b * SEQ;
  for (int i = t; i < SEQ + 2; i += NT) xs[i] = (i < SEQ) ? xrow[i] : 0.f;
  if (t < QBUF) hq[0][t] = 0;

  // ---- weight quantization (one-time) ----
  // Lane (n,quad) holds W[k = kt*64 + quad*16 + i][col=n], kt in {0,1}.
  // All three gates: single i8, per-row scale 126/rowmax. h is single i8
  // (h*127 rounded).
  int4v Wr[2], Wz[2], Wn[2];
  float kr, kz, kn;
#pragma unroll
  for (int g = 0; g < 3; ++g) {
    const float* row = w_hh + (size_t)(g * 128 + u) * 128;
    float wv[32];
    float m = 0.f;
#pragma unroll
    for (int kt = 0; kt < 2; ++kt)
#pragma unroll
      for (int i = 0; i < 16; ++i) {
        const float v = row[kt * 64 + quad * 16 + i];
        wv[kt * 16 + i] = v;
        m = fmaxf(m, fabsf(v));
      }
    m = fmaxf(m, __shfl_xor(m, 16));   // rowmax across the 4 quads
    m = fmaxf(m, __shfl_xor(m, 32));
    const float Sw = 126.f / m;
#pragma unroll
    for (int kt = 0; kt < 2; ++kt) {
      int ph[4] = {0, 0, 0, 0};
#pragma unroll
      for (int i = 0; i < 16; ++i) {
        const int qh = __float2int_rn(wv[kt * 16 + i] * Sw);
        ph[i >> 2] |= (qh & 255) << (8 * (i & 3));
      }
      const int4v vh = {ph[0], ph[1], ph[2], ph[3]};
      if (g == 0) Wr[kt] = vh;
      else if (g == 1) Wz[kt] = vh;
      else Wn[kt] = vh;
    }
    const float ksc = m / 16002.f;     // m/(126*127)
    if (g == 0) kr = NLOG2E * ksc;
    else if (g == 1) kz = NLOG2E * ksc;
    else kn = N2LOG2E * ksc;
  }

  // pre-scaled per-unit scalars (input preact + biases folded into seeds)
  const float bcr = NLOG2E * (b_ih[u] + b_hh[u]);
  const float bcz = NLOG2E * (b_ih[128 + u] + b_hh[128 + u]);
  const float bin_ = N2LOG2E * b_ih[256 + u];
  const float bhn_s = N2LOG2E * b_hh[256 + u];
  const float wir = NLOG2E * w_ih[u];
  const float wiz = NLOG2E * w_ih[128 + u];
  const float win = N2LOG2E * w_ih[256 + u];

  // per-lane A-read base (bytes); hoisted, loop-invariant h-store address:
  // quad0 -> hi8 at u; quads 1,2,3 -> dump at 256+L (never read)
  const int ib = quad * 16;
  const int haddr = (quad == 0) ? u : (256 + L);

  // h is carried ONLY as h127 = h * 127 (f32). The store is round(h127);
  // the epilogue multiplies by 1/127 once. Same recurrence, scaled.
  float h127 = 0.f;

  // persistent zero C-operand: all 6 MFMAs start from zero4 (independent,
  // no dep chains); the K=64 halves are summed with exact integer adds.
  int4v zero4 = {0, 0, 0, 0};

  __syncthreads();

#define MI(A, B, C) __builtin_amdgcn_mfma_i32_16x16x64_i8(A, B, C, 0, 0, 0)

  // One step. All 6 MFMAs are independent (C = zero4, fresh dests) so they
  // issue back-to-back; integer adds of the [0] regs reconstruct the K=128
  // dots bit-identically to chaining. Issue order r, n, z = consumption
  // order (r feeds the n-preact; z needed only at the final blend).
#define STEP(RD, WR, XT)                                                       \
  {                                                                            \
    const float xt = (XT);                                                     \
    const int4v Ai0 = *(const int4v*)&hq[RD][ib];                              \
    const int4v Ai1 = *(const int4v*)&hq[RD][ib + 64];                         \
    const float sr = fmaf(xt, wir, bcr);                                       \
    const float sz = fmaf(xt, wiz, bcz);                                       \
    const float in_s = fmaf(xt, win, bin_);                                    \
    const int4v cr0 = MI(Ai0, Wr[0], zero4);                                   \
    const int4v cr1 = MI(Ai1, Wr[1], zero4);                                   \
    const int4v ca0 = MI(Ai0, Wn[0], zero4);                                   \
    const int4v ca1 = MI(Ai1, Wn[1], zero4);                                   \
    const int4v cz0 = MI(Ai0, Wz[0], zero4);                                   \
    const int4v cz1 = MI(Ai1, Wz[1], zero4);                                   \
    const float r = __builtin_amdgcn_rcpf(                                     \
        1.f + __builtin_amdgcn_exp2f(fmaf((float)(cr0[0] + cr1[0]), kr, sr))); \
    const float pn = fmaf((float)(ca0[0] + ca1[0]), kn, bhn_s);                \
    const float e = __builtin_amdgcn_exp2f(fmaf(r, pn, in_s));                 \
    const float rcpv = __builtin_amdgcn_rcpf(1.f + e);                         \
    const float nn127 = fmaf(254.f, rcpv, -127.f);   /* tanh*127 */            \
    const float z = __builtin_amdgcn_rcpf(                                     \
        1.f + __builtin_amdgcn_exp2f(fmaf((float)(cz0[0] + cz1[0]), kz, sz))); \
    h127 = fmaf(z, h127 - nn127, nn127);                                       \
    const int hi8 = __float2int_rn(h127);                                      \
    hq[WR][haddr] = (char)hi8;                                                 \
    __syncthreads();                                                           \
  }

  float x0 = xs[0], x1 = xs[1];
  for (int s = 0; s < SEQ; s += 2) {
    const float2 xnext = *(const float2*)&xs[s + 2];  // LDS prefetch, 1 b64
    STEP(0, 1, x0);
    STEP(1, 0, x1);
    x0 = xnext.x;
    x1 = xnext.y;
  }
#undef STEP
#undef MI

  // epilogue: out[b] = relu(h_T) . w_fc + b_fc   (h = h127/127, exact f32)
  float v = (quad == 0)
                ? fmaxf(h127 * 0.007874015748031496f, 0.f) * w_fc[u]
                : 0.f;
#pragma unroll
  for (int off = 1; off < 64; off <<= 1) v += __shfl_xor(v, off);
  if (L == 0) red[w] = v;
  __syncthreads();
  if (t == 0) {
    float sum = 0.f;
#pragma unroll
    for (int k = 0; k < 8; ++k) sum += red[k];
    out[b] = sum + b_fc[0];
  }
}

extern "C" void kernel_launch(void* const* d_in, const int* in_sizes, int n_in,
                              void* d_out, int out_size, void* d_ws, size_t ws_size,
                              hipStream_t stream) {
  const float* x    = (const float*)d_in[0];
  const float* w_ih = (const float*)d_in[1];
  const float* w_hh = (const float*)d_in[2];
  const float* b_ih = (const float*)d_in[3];
  const float* b_hh = (const float*)d_in[4];
  const float* w_fc = (const float*)d_in[5];
  const float* b_fc = (const float*)d_in[6];
  gru_kernel<<<256, NT, 0, stream>>>(x, w_ih, w_hh, b_ih, b_hh, w_fc, b_fc,
                                     (float*)d_out);
}

// Round 13
// 307.186 us; speedup vs baseline: 1.0732x; 1.0732x over previous
//
#include <hip/hip_runtime.h>

#define SEQ 1024
#define NT 512   // 8 waves; wave w owns units [16w,16w+16) for r,z,n

typedef int int4v __attribute__((ext_vector_type(4)));  // i8 MFMA frags/accum

// i8 h buffer (bytes): hi8 at [0..127], dump at [256..319].
// A-reads (b128): 4 distinct addrs x 16-lane broadcast, banks 0-15 (Ai0)
// and 16-31 (Ai1): conflict-free.
#define QBUF 384

#define NLOG2E  (-1.4426950408889634f)   // -log2(e): sigmoid via exp2
#define N2LOG2E (-2.8853900817779268f)   // -2*log2(e): tanh via exp2

__global__ __launch_bounds__(NT, 2)
void gru_kernel(const float* __restrict__ x,     // [B, S, 1]
                const float* __restrict__ w_ih,  // [3H, 1]
                const float* __restrict__ w_hh,  // [3H, H]
                const float* __restrict__ b_ih,  // [3H]
                const float* __restrict__ b_hh,  // [3H]
                const float* __restrict__ w_fc,  // [1, H]
                const float* __restrict__ b_fc,  // [1]
                float* __restrict__ out)         // [B, 1]
{
  __shared__ __align__(8) float xs[SEQ + 2];
  __shared__ __align__(16) char hq[2][QBUF];
  __shared__ float red[8];

  const int t = threadIdx.x;
  const int b = blockIdx.x;
  const int w = t >> 6;          // wave 0..7
  const int L = t & 63;          // lane
  const int n = L & 15;          // MFMA col (unit) == A-row
  const int quad = L >> 4;       // k-slice / C-row group
  const int u = 16 * w + n;      // hidden unit

  // stage x[b,:] (coalesced); pad 2 zeros for the register prefetch
  const float* xrow = x + (size_t)b * SEQ;
  for (int i = t; i < SEQ + 2; i += NT) xs[i] = (i < SEQ) ? xrow[i] : 0.f;
  if (t < QBUF) hq[0][t] = 0;

  // ---- weight quantization (one-time) ----
  // Lane (n,quad) holds W[k = kt*64 + quad*16 + i][col=n], kt in {0,1}.
  // All three gates: single i8, per-row scale 126/rowmax. h is single i8
  // (h*127 rounded).
  int4v Wr[2], Wz[2], Wn[2];
  float kr, kz, kn;
#pragma unroll
  for (int g = 0; g < 3; ++g) {
    const float* row = w_hh + (size_t)(g * 128 + u) * 128;
    float wv[32];
    float m = 0.f;
#pragma unroll
    for (int kt = 0; kt < 2; ++kt)
#pragma unroll
      for (int i = 0; i < 16; ++i) {
        const float v = row[kt * 64 + quad * 16 + i];
        wv[kt * 16 + i] = v;
        m = fmaxf(m, fabsf(v));
      }
    m = fmaxf(m, __shfl_xor(m, 16));   // rowmax across the 4 quads
    m = fmaxf(m, __shfl_xor(m, 32));
    const float Sw = 126.f / m;
#pragma unroll
    for (int kt = 0; kt < 2; ++kt) {
      int ph[4] = {0, 0, 0, 0};
#pragma unroll
      for (int i = 0; i < 16; ++i) {
        const int qh = __float2int_rn(wv[kt * 16 + i] * Sw);
        ph[i >> 2] |= (qh & 255) << (8 * (i & 3));
      }
      const int4v vh = {ph[0], ph[1], ph[2], ph[3]};
      if (g == 0) Wr[kt] = vh;
      else if (g == 1) Wz[kt] = vh;
      else Wn[kt] = vh;
    }
    const float ksc = m / 16002.f;     // m/(126*127)
    if (g == 0) kr = NLOG2E * ksc;
    else if (g == 1) kz = NLOG2E * ksc;
    else kn = N2LOG2E * ksc;
  }

  // pre-scaled per-unit scalars (input preact + biases folded into seeds)
  const float bcr = NLOG2E * (b_ih[u] + b_hh[u]);
  const float bcz = NLOG2E * (b_ih[128 + u] + b_hh[128 + u]);
  const float bin_ = N2LOG2E * b_ih[256 + u];
  const float bhn_s = N2LOG2E * b_hh[256 + u];
  const float wir = NLOG2E * w_ih[u];
  const float wiz = NLOG2E * w_ih[128 + u];
  const float win = N2LOG2E * w_ih[256 + u];

  // per-lane A-read base (bytes); hoisted, loop-invariant h-store address:
  // quad0 -> hi8 at u; quads 1,2,3 -> dump at 256+L (never read)
  const int ib = quad * 16;
  const int haddr = (quad == 0) ? u : (256 + L);

  // h is carried ONLY as h127 = h * 127 (f32). The store is round(h127);
  // the epilogue multiplies by 1/127 once. Same recurrence, scaled.
  float h127 = 0.f;

  // persistent zero C-operand: MFMAs write fresh dests (D != C), so no
  // per-step accumulator zeroing movs are needed.
  int4v zero4 = {0, 0, 0, 0};

  __syncthreads();

#define MI(A, B, C) __builtin_amdgcn_mfma_i32_16x16x64_i8(A, B, C, 0, 0, 0)

  // One step. MFMA order r, n, z = dot-consumption order: r feeds the
  // n-preact (longest chain, starts earliest), z is needed only at the
  // final blend (its short sigmoid chain hides under n's exp2/rcp).
  // Chained K=64 pairs: the in-pipe C-accumulate is free (R11 showed
  // splitting them onto the VALU regresses). Only accum reg [0] is read
  // (all C rows identical: A-rows replicated).
#define STEP(RD, WR, XT)                                                       \
  {                                                                            \
    const float xt = (XT);                                                     \
    const int4v Ai0 = *(const int4v*)&hq[RD][ib];                              \
    const int4v Ai1 = *(const int4v*)&hq[RD][ib + 64];                         \
    const float sr = fmaf(xt, wir, bcr);                                       \
    const float sz = fmaf(xt, wiz, bcz);                                       \
    const float in_s = fmaf(xt, win, bin_);                                    \
    int4v cr = MI(Ai0, Wr[0], zero4);                                          \
    cr = MI(Ai1, Wr[1], cr);                                                   \
    int4v ca = MI(Ai0, Wn[0], zero4);                                          \
    ca = MI(Ai1, Wn[1], ca);                                                   \
    int4v cz = MI(Ai0, Wz[0], zero4);                                          \
    cz = MI(Ai1, Wz[1], cz);                                                   \
    const float r = __builtin_amdgcn_rcpf(                                     \
        1.f + __builtin_amdgcn_exp2f(fmaf((float)cr[0], kr, sr)));             \
    const float pn = fmaf((float)ca[0], kn, bhn_s);                            \
    const float e = __builtin_amdgcn_exp2f(fmaf(r, pn, in_s));                 \
    const float rcpv = __builtin_amdgcn_rcpf(1.f + e);                         \
    const float nn127 = fmaf(254.f, rcpv, -127.f);   /* tanh*127 */            \
    const float z = __builtin_amdgcn_rcpf(                                     \
        1.f + __builtin_amdgcn_exp2f(fmaf((float)cz[0], kz, sz)));             \
    h127 = fmaf(z, h127 - nn127, nn127);                                       \
    const int hi8 = __float2int_rn(h127);                                      \
    hq[WR][haddr] = (char)hi8;                                                 \
    __syncthreads();                                                           \
  }

  float x0 = xs[0], x1 = xs[1];
  for (int s = 0; s < SEQ; s += 2) {
    const float2 xnext = *(const float2*)&xs[s + 2];  // LDS prefetch, 1 b64
    STEP(0, 1, x0);
    STEP(1, 0, x1);
    x0 = xnext.x;
    x1 = xnext.y;
  }
#undef STEP
#undef MI

  // epilogue: out[b] = relu(h_T) . w_fc + b_fc   (h = h127/127, exact f32)
  float v = (quad == 0)
                ? fmaxf(h127 * 0.007874015748031496f, 0.f) * w_fc[u]
                : 0.f;
#pragma unroll
  for (int off = 1; off < 64; off <<= 1) v += __shfl_xor(v, off);
  if (L == 0) red[w] = v;
  __syncthreads();
  if (t == 0) {
    float sum = 0.f;
#pragma unroll
    for (int k = 0; k < 8; ++k) sum += red[k];
    out[b] = sum + b_fc[0];
  }
}

extern "C" void kernel_launch(void* const* d_in, const int* in_sizes, int n_in,
                              void* d_out, int out_size, void* d_ws, size_t ws_size,
                              hipStream_t stream) {
  const float* x    = (const float*)d_in[0];
  const float* w_ih = (const float*)d_in[1];
  const float* w_hh = (const float*)d_in[2];
  const float* b_ih = (const float*)d_in[3];
  const float* b_hh = (const float*)d_in[4];
  const float* w_fc = (const float*)d_in[5];
  const float* b_fc = (const float*)d_in[6];
  gru_kernel<<<256, NT, 0, stream>>>(x, w_ih, w_hh, b_ih, b_hh, w_fc, b_fc,
                                     (float*)d_out);
}